// Round 7
// baseline (530.444 us; speedup 1.0000x reference)
//
#include <hip/hip_runtime.h>
#include <hip/hip_bf16.h>

#define NN 25000
#define NE 100000
#define FIN 32
#define DD 64
#define NG 1000

typedef unsigned short u16;
typedef __attribute__((ext_vector_type(8))) short short8;
typedef __attribute__((ext_vector_type(4))) float f32x4;

__device__ __forceinline__ float b2f(u16 u) {
    union { unsigned int i; float f; } v; v.i = ((unsigned int)u) << 16; return v.f;
}
__device__ __forceinline__ u16 f2b(float f) {
    __hip_bfloat16 h = __float2bfloat16(f);
    return __builtin_bit_cast(u16, h);
}
// edge_index may be int64 read as int32 words: odd words would all be 0.
__device__ __forceinline__ bool idx_is_i64(const int* e) {
    return (e[1] == 0) & (e[3] == 0) & (e[5] == 0) & (e[7] == 0) & (e[9] == 0);
}
__device__ __forceinline__ int ld_src(const int* e, int i, bool i64) {
    return i64 ? e[2 * i] : e[i];
}
__device__ __forceinline__ int ld_dst(const int* e, int i, bool i64) {
    return i64 ? e[2 * (NE + i)] : e[NE + i];
}

// ---- prep: Bt (We2 reshaped+transposed + be2 rows, bf16); zero agg/pooled ---------------
__global__ __launch_bounds__(256) void k_prep(const float* __restrict__ We2,
                                              const float* __restrict__ be2,
                                              float* __restrict__ agg,
                                              float* __restrict__ pooled,
                                              u16* __restrict__ Bt) {
    int tid = blockIdx.x * 256 + threadIdx.x;
    int stride = gridDim.x * 256;
    // Bt[o][r]: r = k*64+i (<4096) -> We2[k, i*64+o]; r-4096 = i -> be2[i*64+o]
    for (int idx = tid; idx < 64 * 4160; idx += stride) {
        int o = idx / 4160;
        int r = idx - o * 4160;
        float v;
        if (r < 4096) v = We2[(r >> 6) * 4096 + (r & 63) * 64 + o];
        else          v = be2[(r - 4096) * 64 + o];
        Bt[idx] = f2b(v);
    }
    for (int idx = tid; idx < NN * DD; idx += stride) agg[idx] = 0.f;
    for (int idx = tid; idx < NG * DD; idx += stride) pooled[idx] = 0.f;
}

// ---- lin0: x1 = relu(x @ W0 + b0), stored bf16 ------------------------------------------
__global__ __launch_bounds__(256) void k_lin0(const float* __restrict__ x,
                                              const float* __restrict__ W0,
                                              const float* __restrict__ b0,
                                              u16* __restrict__ x1b) {
    __shared__ float sW[FIN * DD];
    __shared__ float sx[4 * FIN];
    int tid = threadIdx.x;
    for (int i = tid; i < FIN * DD; i += 256) sW[i] = W0[i];
    int nbase = blockIdx.x * 4;
    for (int i = tid; i < 4 * FIN; i += 256) {
        int nl = i >> 5, f = i & 31;
        int n = nbase + nl;
        sx[i] = (n < NN) ? x[n * FIN + f] : 0.f;
    }
    __syncthreads();
    int lane = tid & 63, nl = tid >> 6;
    int n = nbase + nl;
    if (n < NN) {
        float acc = b0[lane];
        #pragma unroll
        for (int f = 0; f < FIN; f++) acc += sx[nl * FIN + f] * sW[f * DD + lane];
        x1b[n * DD + lane] = f2b(fmaxf(acc, 0.f));
    }
}

// ---- fused NNConv message GEMM + scatter -------------------------------------------------
// msg[e,o] = sum_{k,i} t[e,k]*xs[e,i]*We2[k,i*64+o] + sum_i xs[e,i]*be2[i*64+o]
//          = A[E,4160] @ B[4160,64]; A generated on the fly, B staged from Bt.
__global__ __launch_bounds__(256, 3) void k_msg(const float* __restrict__ ea,
                                                const int* __restrict__ eidx,
                                                const float* __restrict__ We1,
                                                const float* __restrict__ be1,
                                                const u16* __restrict__ x1b,
                                                const u16* __restrict__ Bt,
                                                float* __restrict__ agg) {
    __shared__ __align__(16) u16 sB[64 * 72];   // [o][r_local], pad 72
    __shared__ __align__(16) u16 sX[128 * 72];  // gathered x1 rows (bf16), pad 72
    __shared__ u16 sT[64 * 128];                // t transposed [k][e]
    __shared__ float sWe1[8 * 64];
    __shared__ float sbe1[64];
    const int tid = threadIdx.x;
    const int lane = tid & 63, wv = tid >> 6;
    const int ll = lane & 15, quad = lane >> 4;
    const int e0 = blockIdx.x * 128;
    const bool i64 = idx_is_i64(eidx);

    for (int i = tid; i < 512; i += 256) sWe1[i] = We1[i];
    if (tid < 64) sbe1[tid] = be1[tid];

    // phase 1: gather x1 rows (bf16) for 128 edges; load edge_attr to regs
    const int eg2 = e0 + (tid >> 1);
    {
        int i0 = (tid & 1) * 32;
        if (eg2 < NE) {
            int sv = ld_src(eidx, eg2, i64);
            const u16* xr = x1b + sv * 64 + i0;
            #pragma unroll
            for (int c = 0; c < 4; c++)
                *(uint4*)&sX[(tid >> 1) * 72 + i0 + c * 8] = *(const uint4*)(xr + c * 8);
        } else {
            uint4 z = make_uint4(0, 0, 0, 0);
            #pragma unroll
            for (int c = 0; c < 4; c++)
                *(uint4*)&sX[(tid >> 1) * 72 + i0 + c * 8] = z;
        }
    }
    float eav[8];
    if (eg2 < NE) {
        f32x4 v0 = *(const f32x4*)(ea + eg2 * 8);
        f32x4 v1 = *(const f32x4*)(ea + eg2 * 8 + 4);
        #pragma unroll
        for (int f = 0; f < 4; f++) { eav[f] = v0[f]; eav[4 + f] = v1[f]; }
    } else {
        #pragma unroll
        for (int f = 0; f < 8; f++) eav[f] = 0.f;
    }
    __syncthreads();

    // phase 2: t[e,k] = relu(ea @ We1 + be1) (f32 math), stored bf16 transposed [k][e]
    {
        int e = tid >> 1, k0 = (tid & 1) * 32;
        for (int kk = 0; kk < 32; kk++) {
            int k = k0 + kk;
            float acc = sbe1[k];
            #pragma unroll
            for (int f = 0; f < 8; f++) acc += eav[f] * sWe1[f * 64 + k];
            sT[k * 128 + e] = (eg2 < NE) ? f2b(fmaxf(acc, 0.f)) : (u16)0;
        }
    }
    __syncthreads();

    // hoist xs fragments (constant across the k-loop)
    float xsf[2][2][8];
    #pragma unroll
    for (int rt = 0; rt < 2; rt++)
        #pragma unroll
        for (int s = 0; s < 2; s++) {
            const u16* p = &sX[(wv * 32 + rt * 16 + ll) * 72 + s * 32 + quad * 8];
            #pragma unroll
            for (int j = 0; j < 8; j++) xsf[rt][s][j] = b2f(p[j]);
        }

    f32x4 acc[2][4];
    #pragma unroll
    for (int rt = 0; rt < 2; rt++)
        #pragma unroll
        for (int c = 0; c < 4; c++) acc[rt][c] = (f32x4){0.f, 0.f, 0.f, 0.f};

    for (int kc = 0; kc < 65; kc++) {
        __syncthreads();
        // stage B chunk: rows r = kc*64 .. +63 as sB[o][r_local]
        {
            int o = tid >> 2, seg = tid & 3;
            const u16* gp = Bt + o * 4160 + kc * 64 + seg * 16;
            uint4 v0 = *(const uint4*)gp;
            uint4 v1 = *(const uint4*)(gp + 8);
            *(uint4*)&sB[o * 72 + seg * 16] = v0;
            *(uint4*)&sB[o * 72 + seg * 16 + 8] = v1;
        }
        float tk0, tk1;
        if (kc < 64) {
            tk0 = b2f(sT[kc * 128 + wv * 32 + ll]);
            tk1 = b2f(sT[kc * 128 + wv * 32 + 16 + ll]);
        } else { tk0 = 1.f; tk1 = 1.f; }   // bias block: A = xs
        __syncthreads();

        #pragma unroll
        for (int s = 0; s < 2; s++) {
            short8 a0, a1;
            #pragma unroll
            for (int j = 0; j < 8; j++) {
                a0[j] = (short)f2b(tk0 * xsf[0][s][j]);
                a1[j] = (short)f2b(tk1 * xsf[1][s][j]);
            }
            #pragma unroll
            for (int c = 0; c < 4; c++) {
                short8 b = *(const short8*)&sB[(c * 16 + ll) * 72 + s * 32 + quad * 8];
                acc[0][c] = __builtin_amdgcn_mfma_f32_16x16x32_bf16(a0, b, acc[0][c], 0, 0, 0);
                acc[1][c] = __builtin_amdgcn_mfma_f32_16x16x32_bf16(a1, b, acc[1][c], 0, 0, 0);
            }
        }
    }

    // epilogue: C row = quad*4+reg, col = c*16+ll; scatter-add into agg[dst]
    #pragma unroll
    for (int rt = 0; rt < 2; rt++) {
        int ebase = e0 + wv * 32 + rt * 16 + quad * 4;
        #pragma unroll
        for (int r = 0; r < 4; r++) {
            int eg = ebase + r;
            if (eg < NE) {
                int d = ld_dst(eidx, eg, i64);
                #pragma unroll
                for (int c = 0; c < 4; c++)
                    atomicAdd(&agg[d * 64 + c * 16 + ll], acc[rt][c][r]);
            }
        }
    }
}

// ---- x2 = relu(x1@Wroot + agg + bconv); GRU step; pooled scatter -------------------------
// LDS: sWi 27648 + sWh 27648 + sV 2048 = 57344 B. Wroot column in 64 f32 regs/lane.
__global__ __launch_bounds__(256) void k_gru(const u16* __restrict__ x1b,
                                             const float* __restrict__ agg,
                                             const float* __restrict__ Wroot,
                                             const float* __restrict__ bconv,
                                             const float* __restrict__ Wi,
                                             const float* __restrict__ Wh,
                                             const float* __restrict__ bi,
                                             const float* __restrict__ bh,
                                             const int* __restrict__ batch,
                                             float* __restrict__ pooled) {
    __shared__ __align__(16) u16 sWi[192 * 72];  // [j][i] bf16, pad 72
    __shared__ __align__(16) u16 sWh[192 * 72];
    __shared__ __align__(16) float sV[4][2][64]; // per-wave h and x2
    int tid = threadIdx.x;
    for (int idx = tid; idx < 192 * 64; idx += 256) {
        int j = idx >> 6, i = idx & 63;
        sWi[j * 72 + i] = f2b(Wi[idx]);
        sWh[j * 72 + i] = f2b(Wh[idx]);
    }
    __syncthreads();
    int lane = tid & 63, wv = tid >> 6;
    float wr[64];
    #pragma unroll
    for (int i = 0; i < 64; i++) wr[i] = Wroot[i * 64 + lane];
    float bcv = bconv[lane];
    float biv[3], bhv[3];
    #pragma unroll
    for (int g = 0; g < 3; g++) { biv[g] = bi[g * 64 + lane]; bhv[g] = bh[g * 64 + lane]; }

    for (int n = blockIdx.x * 4 + wv; n < NN; n += gridDim.x * 4) {
        float h = b2f(x1b[n * 64 + lane]);
        sV[wv][0][lane] = h;
        float acc = agg[n * 64 + lane] + bcv;
        #pragma unroll
        for (int ic = 0; ic < 64; ic += 8) {
            f32x4 h0 = *(f32x4*)&sV[wv][0][ic];
            f32x4 h1 = *(f32x4*)&sV[wv][0][ic + 4];
            acc += wr[ic + 0] * h0[0] + wr[ic + 1] * h0[1]
                 + wr[ic + 2] * h0[2] + wr[ic + 3] * h0[3]
                 + wr[ic + 4] * h1[0] + wr[ic + 5] * h1[1]
                 + wr[ic + 6] * h1[2] + wr[ic + 7] * h1[3];
        }
        float x2 = fmaxf(acc, 0.f);
        sV[wv][1][lane] = x2;
        float gi[3], gh[3];
        #pragma unroll
        for (int g = 0; g < 3; g++) { gi[g] = biv[g]; gh[g] = bhv[g]; }
        #pragma unroll
        for (int ic = 0; ic < 64; ic += 8) {
            f32x4 xa = *(f32x4*)&sV[wv][1][ic];
            f32x4 xb = *(f32x4*)&sV[wv][1][ic + 4];
            f32x4 ha = *(f32x4*)&sV[wv][0][ic];
            f32x4 hb = *(f32x4*)&sV[wv][0][ic + 4];
            #pragma unroll
            for (int g = 0; g < 3; g++) {
                short8 wi8 = *(const short8*)&sWi[(g * 64 + lane) * 72 + ic];
                short8 wh8 = *(const short8*)&sWh[(g * 64 + lane) * 72 + ic];
                gi[g] += b2f((u16)wi8[0]) * xa[0] + b2f((u16)wi8[1]) * xa[1]
                       + b2f((u16)wi8[2]) * xa[2] + b2f((u16)wi8[3]) * xa[3]
                       + b2f((u16)wi8[4]) * xb[0] + b2f((u16)wi8[5]) * xb[1]
                       + b2f((u16)wi8[6]) * xb[2] + b2f((u16)wi8[7]) * xb[3];
                gh[g] += b2f((u16)wh8[0]) * ha[0] + b2f((u16)wh8[1]) * ha[1]
                       + b2f((u16)wh8[2]) * ha[2] + b2f((u16)wh8[3]) * ha[3]
                       + b2f((u16)wh8[4]) * hb[0] + b2f((u16)wh8[5]) * hb[1]
                       + b2f((u16)wh8[6]) * hb[2] + b2f((u16)wh8[7]) * hb[3];
            }
        }
        float rg = 1.f / (1.f + __expf(-(gi[0] + gh[0])));
        float zg = 1.f / (1.f + __expf(-(gi[1] + gh[1])));
        float ng = tanhf(gi[2] + rg * gh[2]);
        float hn = (1.f - zg) * ng + zg * h;
        atomicAdd(&pooled[batch[n] * 64 + lane], hn);
    }
}

// ---- heads: two 3-layer MLPs over pooled; output FLOAT32 ---------------------------------
__global__ __launch_bounds__(256) void k_heads(const float* __restrict__ pooled,
                                               const float* __restrict__ W11, const float* __restrict__ b11,
                                               const float* __restrict__ W12, const float* __restrict__ b12,
                                               const float* __restrict__ W13, const float* __restrict__ b13,
                                               const float* __restrict__ W21, const float* __restrict__ b21,
                                               const float* __restrict__ W22, const float* __restrict__ b22,
                                               const float* __restrict__ W23, const float* __restrict__ b23,
                                               float* __restrict__ out) {
    __shared__ float sV[4][64];
    __shared__ float sA[4][64];
    int tid = threadIdx.x, lane = tid & 63, wv = tid >> 6;
    int g = blockIdx.x * 4 + wv;
    if (g >= NG) return;
    float p = pooled[g * 64 + lane];
    sV[wv][lane] = p;
    float y[2];
    const float* W1s[2] = {W11, W21}; const float* b1s[2] = {b11, b21};
    const float* W2s[2] = {W12, W22}; const float* b2s[2] = {b12, b22};
    const float* W3s[2] = {W13, W23}; const float* b3s[2] = {b13, b23};
    #pragma unroll
    for (int hd = 0; hd < 2; hd++) {
        float a = b1s[hd][lane];
        for (int i = 0; i < 64; i++) a += sV[wv][i] * W1s[hd][i * 64 + lane];
        a = fmaxf(a, 0.f);
        sA[wv][lane] = a;
        float a2 = b2s[hd][lane];
        for (int i = 0; i < 64; i++) a2 += sA[wv][i] * W2s[hd][i * 64 + lane];
        a2 = fmaxf(a2, 0.f);
        float part = a2 * W3s[hd][lane];
        #pragma unroll
        for (int m = 32; m > 0; m >>= 1) part += __shfl_xor(part, m, 64);
        y[hd] = part + b3s[hd][0];
    }
    if (lane == 0) {
        out[g * 2 + 0] = y[0];   // f32 output — reference output dtype is float32
        out[g * 2 + 1] = y[1];
    }
}

extern "C" void kernel_launch(void* const* d_in, const int* in_sizes, int n_in,
                              void* d_out, int out_size, void* d_ws, size_t ws_size,
                              hipStream_t stream) {
    const float* x     = (const float*)d_in[0];
    const int* eidx    = (const int*)d_in[1];
    const float* ea    = (const float*)d_in[2];
    const int* batch   = (const int*)d_in[3];
    const float* W0    = (const float*)d_in[4];  const float* b0    = (const float*)d_in[5];
    const float* We1   = (const float*)d_in[6];  const float* be1   = (const float*)d_in[7];
    const float* We2   = (const float*)d_in[8];  const float* be2   = (const float*)d_in[9];
    const float* Wroot = (const float*)d_in[10]; const float* bconv = (const float*)d_in[11];
    const float* Wi    = (const float*)d_in[12]; const float* Wh    = (const float*)d_in[13];
    const float* bi    = (const float*)d_in[14]; const float* bh    = (const float*)d_in[15];
    const float* W11   = (const float*)d_in[16]; const float* b11   = (const float*)d_in[17];
    const float* W12   = (const float*)d_in[18]; const float* b12   = (const float*)d_in[19];
    const float* W13   = (const float*)d_in[20]; const float* b13   = (const float*)d_in[21];
    const float* W21   = (const float*)d_in[22]; const float* b21   = (const float*)d_in[23];
    const float* W22   = (const float*)d_in[24]; const float* b22   = (const float*)d_in[25];
    const float* W23   = (const float*)d_in[26]; const float* b23   = (const float*)d_in[27];
    float* out = (float*)d_out;

    // workspace: total 10,388,480 B
    char* ws = (char*)d_ws;
    float* agg    = (float*)(ws);                       // 6,400,000 B
    u16*   x1b    = (u16*)(ws + 6400000);               // 3,200,000 B
    u16*   Bt     = (u16*)(ws + 9600000);               //   532,480 B
    float* pooled = (float*)(ws + 10132480);            //   256,000 B

    hipLaunchKernelGGL(k_prep, dim3(2048), dim3(256), 0, stream, We2, be2, agg, pooled, Bt);
    hipLaunchKernelGGL(k_lin0, dim3(6250), dim3(256), 0, stream, x, W0, b0, x1b);
    hipLaunchKernelGGL(k_msg, dim3(782), dim3(256), 0, stream, ea, eidx, We1, be1, x1b, Bt, agg);
    hipLaunchKernelGGL(k_gru, dim3(512), dim3(256), 0, stream, x1b, agg, Wroot, bconv,
                       Wi, Wh, bi, bh, batch, pooled);
    hipLaunchKernelGGL(k_heads, dim3(250), dim3(256), 0, stream, pooled,
                       W11, b11, W12, b12, W13, b13, W21, b21, W22, b22, W23, b23, out);
}

// Round 8
// 280.282 us; speedup vs baseline: 1.8925x; 1.8925x over previous
//
#include <hip/hip_runtime.h>
#include <hip/hip_bf16.h>

#define NN 25000
#define NE 100000
#define FIN 32
#define DD 64
#define NG 1000

typedef unsigned short u16;
typedef __attribute__((ext_vector_type(8))) short short8;
typedef __attribute__((ext_vector_type(4))) float f32x4;

__device__ __forceinline__ float b2f(u16 u) {
    union { unsigned int i; float f; } v; v.i = ((unsigned int)u) << 16; return v.f;
}
__device__ __forceinline__ u16 f2b(float f) {
    __hip_bfloat16 h = __float2bfloat16(f);
    return __builtin_bit_cast(u16, h);
}
// edge_index may be int64 read as int32 words: odd words would all be 0.
__device__ __forceinline__ bool idx_is_i64(const int* e) {
    return (e[1] == 0) & (e[3] == 0) & (e[5] == 0) & (e[7] == 0) & (e[9] == 0);
}
__device__ __forceinline__ int ld_src(const int* e, int i, bool i64) {
    return i64 ? e[2 * i] : e[i];
}
__device__ __forceinline__ int ld_dst(const int* e, int i, bool i64) {
    return i64 ? e[2 * (NE + i)] : e[NE + i];
}

// ---- prep: Bt (We2 reshaped+transposed + be2 rows, bf16); zero agg/pooled ---------------
__global__ __launch_bounds__(256) void k_prep(const float* __restrict__ We2,
                                              const float* __restrict__ be2,
                                              float* __restrict__ agg,
                                              float* __restrict__ pooled,
                                              u16* __restrict__ Bt) {
    int tid = blockIdx.x * 256 + threadIdx.x;
    int stride = gridDim.x * 256;
    for (int idx = tid; idx < 64 * 4160; idx += stride) {
        int o = idx / 4160;
        int r = idx - o * 4160;
        float v;
        if (r < 4096) v = We2[(r >> 6) * 4096 + (r & 63) * 64 + o];
        else          v = be2[(r - 4096) * 64 + o];
        Bt[idx] = f2b(v);
    }
    for (int idx = tid; idx < NN * DD; idx += stride) agg[idx] = 0.f;
    for (int idx = tid; idx < NG * DD; idx += stride) pooled[idx] = 0.f;
}

// ---- lin0: x1 = relu(x @ W0 + b0), stored bf16 ------------------------------------------
__global__ __launch_bounds__(256) void k_lin0(const float* __restrict__ x,
                                              const float* __restrict__ W0,
                                              const float* __restrict__ b0,
                                              u16* __restrict__ x1b) {
    __shared__ float sW[FIN * DD];
    __shared__ float sx[4 * FIN];
    int tid = threadIdx.x;
    for (int i = tid; i < FIN * DD; i += 256) sW[i] = W0[i];
    int nbase = blockIdx.x * 4;
    for (int i = tid; i < 4 * FIN; i += 256) {
        int nl = i >> 5, f = i & 31;
        int n = nbase + nl;
        sx[i] = (n < NN) ? x[n * FIN + f] : 0.f;
    }
    __syncthreads();
    int lane = tid & 63, nl = tid >> 6;
    int n = nbase + nl;
    if (n < NN) {
        float acc = b0[lane];
        #pragma unroll
        for (int f = 0; f < FIN; f++) acc += sx[nl * FIN + f] * sW[f * DD + lane];
        x1b[n * DD + lane] = f2b(fmaxf(acc, 0.f));
    }
}

// ---- fused NNConv message GEMM + scatter (unchanged, verified) ---------------------------
__global__ __launch_bounds__(256, 3) void k_msg(const float* __restrict__ ea,
                                                const int* __restrict__ eidx,
                                                const float* __restrict__ We1,
                                                const float* __restrict__ be1,
                                                const u16* __restrict__ x1b,
                                                const u16* __restrict__ Bt,
                                                float* __restrict__ agg) {
    __shared__ __align__(16) u16 sB[64 * 72];
    __shared__ __align__(16) u16 sX[128 * 72];
    __shared__ u16 sT[64 * 128];
    __shared__ float sWe1[8 * 64];
    __shared__ float sbe1[64];
    const int tid = threadIdx.x;
    const int lane = tid & 63, wv = tid >> 6;
    const int ll = lane & 15, quad = lane >> 4;
    const int e0 = blockIdx.x * 128;
    const bool i64 = idx_is_i64(eidx);

    for (int i = tid; i < 512; i += 256) sWe1[i] = We1[i];
    if (tid < 64) sbe1[tid] = be1[tid];

    const int eg2 = e0 + (tid >> 1);
    {
        int i0 = (tid & 1) * 32;
        if (eg2 < NE) {
            int sv = ld_src(eidx, eg2, i64);
            const u16* xr = x1b + sv * 64 + i0;
            #pragma unroll
            for (int c = 0; c < 4; c++)
                *(uint4*)&sX[(tid >> 1) * 72 + i0 + c * 8] = *(const uint4*)(xr + c * 8);
        } else {
            uint4 z = make_uint4(0, 0, 0, 0);
            #pragma unroll
            for (int c = 0; c < 4; c++)
                *(uint4*)&sX[(tid >> 1) * 72 + i0 + c * 8] = z;
        }
    }
    float eav[8];
    if (eg2 < NE) {
        f32x4 v0 = *(const f32x4*)(ea + eg2 * 8);
        f32x4 v1 = *(const f32x4*)(ea + eg2 * 8 + 4);
        #pragma unroll
        for (int f = 0; f < 4; f++) { eav[f] = v0[f]; eav[4 + f] = v1[f]; }
    } else {
        #pragma unroll
        for (int f = 0; f < 8; f++) eav[f] = 0.f;
    }
    __syncthreads();

    {
        int e = tid >> 1, k0 = (tid & 1) * 32;
        for (int kk = 0; kk < 32; kk++) {
            int k = k0 + kk;
            float acc = sbe1[k];
            #pragma unroll
            for (int f = 0; f < 8; f++) acc += eav[f] * sWe1[f * 64 + k];
            sT[k * 128 + e] = (eg2 < NE) ? f2b(fmaxf(acc, 0.f)) : (u16)0;
        }
    }
    __syncthreads();

    float xsf[2][2][8];
    #pragma unroll
    for (int rt = 0; rt < 2; rt++)
        #pragma unroll
        for (int s = 0; s < 2; s++) {
            const u16* p = &sX[(wv * 32 + rt * 16 + ll) * 72 + s * 32 + quad * 8];
            #pragma unroll
            for (int j = 0; j < 8; j++) xsf[rt][s][j] = b2f(p[j]);
        }

    f32x4 acc[2][4];
    #pragma unroll
    for (int rt = 0; rt < 2; rt++)
        #pragma unroll
        for (int c = 0; c < 4; c++) acc[rt][c] = (f32x4){0.f, 0.f, 0.f, 0.f};

    for (int kc = 0; kc < 65; kc++) {
        __syncthreads();
        {
            int o = tid >> 2, seg = tid & 3;
            const u16* gp = Bt + o * 4160 + kc * 64 + seg * 16;
            uint4 v0 = *(const uint4*)gp;
            uint4 v1 = *(const uint4*)(gp + 8);
            *(uint4*)&sB[o * 72 + seg * 16] = v0;
            *(uint4*)&sB[o * 72 + seg * 16 + 8] = v1;
        }
        float tk0, tk1;
        if (kc < 64) {
            tk0 = b2f(sT[kc * 128 + wv * 32 + ll]);
            tk1 = b2f(sT[kc * 128 + wv * 32 + 16 + ll]);
        } else { tk0 = 1.f; tk1 = 1.f; }
        __syncthreads();

        #pragma unroll
        for (int s = 0; s < 2; s++) {
            short8 a0, a1;
            #pragma unroll
            for (int j = 0; j < 8; j++) {
                a0[j] = (short)f2b(tk0 * xsf[0][s][j]);
                a1[j] = (short)f2b(tk1 * xsf[1][s][j]);
            }
            #pragma unroll
            for (int c = 0; c < 4; c++) {
                short8 b = *(const short8*)&sB[(c * 16 + ll) * 72 + s * 32 + quad * 8];
                acc[0][c] = __builtin_amdgcn_mfma_f32_16x16x32_bf16(a0, b, acc[0][c], 0, 0, 0);
                acc[1][c] = __builtin_amdgcn_mfma_f32_16x16x32_bf16(a1, b, acc[1][c], 0, 0, 0);
            }
        }
    }

    #pragma unroll
    for (int rt = 0; rt < 2; rt++) {
        int ebase = e0 + wv * 32 + rt * 16 + quad * 4;
        #pragma unroll
        for (int r = 0; r < 4; r++) {
            int eg = ebase + r;
            if (eg < NE) {
                int d = ld_dst(eidx, eg, i64);
                #pragma unroll
                for (int c = 0; c < 4; c++)
                    atomicAdd(&agg[d * 64 + c * 16 + ll], acc[rt][c][r]);
            }
        }
    }
}

// ---- GRU via MFMA: x2=relu(x1@Wroot+agg+bconv); gi=x2@WiT, gh=h@WhT; gates; segment-
// reduced pooled scatter. 64 nodes/block, 4 waves x 16 rows.
// LDS: sWi 27648 (aliased: WrT 9216 early, hbuf 16640 late) + sWh 27648 + sX2 9216 +
//      sBatch 256 = 64,768 B < 64 KiB... (65536) OK.
__global__ __launch_bounds__(256) void k_gru(const u16* __restrict__ x1b,
                                             const float* __restrict__ agg,
                                             const float* __restrict__ Wroot,
                                             const float* __restrict__ bconv,
                                             const float* __restrict__ Wi,
                                             const float* __restrict__ Wh,
                                             const float* __restrict__ bi,
                                             const float* __restrict__ bh,
                                             const int* __restrict__ batch,
                                             float* __restrict__ pooled) {
    __shared__ __align__(16) u16 sWi[192 * 72];   // phase a: WrT[64][72]; phase d: hbuf f32[64][65]
    __shared__ __align__(16) u16 sWh[192 * 72];
    __shared__ __align__(16) u16 sX2[64 * 72];
    __shared__ int sBatch[64];
    const int tid = threadIdx.x;
    const int lane = tid & 63, wv = tid >> 6;
    const int ll = lane & 15, quad = lane >> 4;
    const int n0 = blockIdx.x * 64;

    // phase a: stage WrT[n][k] = Wroot[k*64+n] (bf16) into sWi region; stage batch
    for (int idx = tid; idx < 4096; idx += 256) {
        int n = idx >> 6, k = idx & 63;
        sWi[n * 72 + k] = f2b(Wroot[k * 64 + n]);
    }
    if (tid < 64) {
        int n = n0 + tid;
        sBatch[tid] = (n < NN) ? batch[n] : -1;
    }
    __syncthreads();

    // GEMM1: x2 = relu(h @ Wroot + agg + bconv), h A-frags from global x1b
    short8 ha[2];   // h A-fragments, reused for GEMM3
    {
        int n = n0 + wv * 16 + ll;
        #pragma unroll
        for (int kc = 0; kc < 2; kc++) {
            if (n < NN) ha[kc] = *(const short8*)(x1b + n * 64 + kc * 32 + quad * 8);
            else        ha[kc] = (short8){0,0,0,0,0,0,0,0};
        }
    }
    f32x4 acc1[4];
    #pragma unroll
    for (int c = 0; c < 4; c++) acc1[c] = (f32x4){0.f, 0.f, 0.f, 0.f};
    #pragma unroll
    for (int kc = 0; kc < 2; kc++) {
        #pragma unroll
        for (int c = 0; c < 4; c++) {
            short8 b = *(const short8*)&sWi[(c * 16 + ll) * 72 + kc * 32 + quad * 8];
            acc1[c] = __builtin_amdgcn_mfma_f32_16x16x32_bf16(ha[kc], b, acc1[c], 0, 0, 0);
        }
    }
    // epilogue: + agg + bconv, relu -> sX2 (bf16, C-layout writes)
    #pragma unroll
    for (int c = 0; c < 4; c++) {
        int col = c * 16 + ll;
        float bcv = bconv[col];
        #pragma unroll
        for (int r = 0; r < 4; r++) {
            int row = wv * 16 + quad * 4 + r;
            int n = n0 + row;
            float v = 0.f;
            if (n < NN) v = fmaxf(acc1[c][r] + agg[n * 64 + col] + bcv, 0.f);
            sX2[row * 72 + col] = f2b(v);
        }
    }
    __syncthreads();

    // phase b: stage Wi/Wh (bf16, row-major pad 72) — overwrites WrT region
    for (int idx = tid; idx < 192 * 64; idx += 256) {
        int j = idx >> 6, i = idx & 63;
        sWi[j * 72 + i] = f2b(Wi[idx]);
        sWh[j * 72 + i] = f2b(Wh[idx]);
    }
    __syncthreads();

    // GEMM2/3: gi = x2 @ Wi^T, gh = h @ Wh^T  (192 cols = 12 col-tiles)
    short8 xa[2];
    #pragma unroll
    for (int kc = 0; kc < 2; kc++)
        xa[kc] = *(const short8*)&sX2[(wv * 16 + ll) * 72 + kc * 32 + quad * 8];

    f32x4 agi[12], agh[12];
    #pragma unroll
    for (int c = 0; c < 12; c++) { agi[c] = (f32x4){0.f,0.f,0.f,0.f}; agh[c] = (f32x4){0.f,0.f,0.f,0.f}; }
    #pragma unroll
    for (int kc = 0; kc < 2; kc++) {
        #pragma unroll
        for (int c = 0; c < 12; c++) {
            short8 bi8 = *(const short8*)&sWi[(c * 16 + ll) * 72 + kc * 32 + quad * 8];
            short8 bh8 = *(const short8*)&sWh[(c * 16 + ll) * 72 + kc * 32 + quad * 8];
            agi[c] = __builtin_amdgcn_mfma_f32_16x16x32_bf16(xa[kc], bi8, agi[c], 0, 0, 0);
            agh[c] = __builtin_amdgcn_mfma_f32_16x16x32_bf16(ha[kc], bh8, agh[c], 0, 0, 0);
        }
    }

    // gates epilogue: d = c0*16+ll; col tiles c0 (r-gate), c0+4 (z), c0+8 (n) same lane
    float hnv[4][4];
    #pragma unroll
    for (int c0 = 0; c0 < 4; c0++) {
        int d = c0 * 16 + ll;
        float bir = bi[d],        bhr = bh[d];
        float biz = bi[64 + d],   bhz = bh[64 + d];
        float bin = bi[128 + d],  bhn = bh[128 + d];
        #pragma unroll
        for (int r = 0; r < 4; r++) {
            int row = wv * 16 + quad * 4 + r;
            int n = n0 + row;
            float gir = agi[c0][r] + bir,     ghr = agh[c0][r] + bhr;
            float giz = agi[c0 + 4][r] + biz, ghz = agh[c0 + 4][r] + bhz;
            float gin = agi[c0 + 8][r] + bin, ghn = agh[c0 + 8][r] + bhn;
            float rg = 1.f / (1.f + __expf(-(gir + ghr)));
            float zg = 1.f / (1.f + __expf(-(giz + ghz)));
            float ng = tanhf(gin + rg * ghn);
            float hv = (n < NN) ? b2f(x1b[n * 64 + d]) : 0.f;
            hnv[c0][r] = (n < NN) ? ((1.f - zg) * ng + zg * hv) : 0.f;
        }
    }
    __syncthreads();   // all sWi/sWh MFMA reads done

    // phase d: hn -> hbuf (aliases sWi), then per-wave sorted-segment reduction -> pooled
    float* hbuf = (float*)sWi;   // [64][65] f32 = 16640 B
    #pragma unroll
    for (int c0 = 0; c0 < 4; c0++) {
        int d = c0 * 16 + ll;
        #pragma unroll
        for (int r = 0; r < 4; r++) {
            int row = wv * 16 + quad * 4 + r;
            hbuf[row * 65 + d] = hnv[c0][r];
        }
    }
    __syncthreads();

    {
        int d = lane;
        float sum = 0.f;
        int pb = sBatch[wv * 16];
        #pragma unroll
        for (int rr = 0; rr < 16; rr++) {
            int row = wv * 16 + rr;
            int b = sBatch[row];
            float v = hbuf[row * 65 + d];
            if (b != pb) {
                if (pb >= 0) atomicAdd(&pooled[pb * 64 + d], sum);
                sum = v; pb = b;
            } else {
                sum += v;
            }
        }
        if (pb >= 0) atomicAdd(&pooled[pb * 64 + d], sum);
    }
}

// ---- heads: two 3-layer MLPs over pooled; output FLOAT32 ---------------------------------
__global__ __launch_bounds__(256) void k_heads(const float* __restrict__ pooled,
                                               const float* __restrict__ W11, const float* __restrict__ b11,
                                               const float* __restrict__ W12, const float* __restrict__ b12,
                                               const float* __restrict__ W13, const float* __restrict__ b13,
                                               const float* __restrict__ W21, const float* __restrict__ b21,
                                               const float* __restrict__ W22, const float* __restrict__ b22,
                                               const float* __restrict__ W23, const float* __restrict__ b23,
                                               float* __restrict__ out) {
    __shared__ float sV[4][64];
    __shared__ float sA[4][64];
    int tid = threadIdx.x, lane = tid & 63, wv = tid >> 6;
    int g = blockIdx.x * 4 + wv;
    if (g >= NG) return;
    float p = pooled[g * 64 + lane];
    sV[wv][lane] = p;
    float y[2];
    const float* W1s[2] = {W11, W21}; const float* b1s[2] = {b11, b21};
    const float* W2s[2] = {W12, W22}; const float* b2s[2] = {b12, b22};
    const float* W3s[2] = {W13, W23}; const float* b3s[2] = {b13, b23};
    #pragma unroll
    for (int hd = 0; hd < 2; hd++) {
        float a = b1s[hd][lane];
        for (int i = 0; i < 64; i++) a += sV[wv][i] * W1s[hd][i * 64 + lane];
        a = fmaxf(a, 0.f);
        sA[wv][lane] = a;
        float a2 = b2s[hd][lane];
        for (int i = 0; i < 64; i++) a2 += sA[wv][i] * W2s[hd][i * 64 + lane];
        a2 = fmaxf(a2, 0.f);
        float part = a2 * W3s[hd][lane];
        #pragma unroll
        for (int m = 32; m > 0; m >>= 1) part += __shfl_xor(part, m, 64);
        y[hd] = part + b3s[hd][0];
    }
    if (lane == 0) {
        out[g * 2 + 0] = y[0];
        out[g * 2 + 1] = y[1];
    }
}

extern "C" void kernel_launch(void* const* d_in, const int* in_sizes, int n_in,
                              void* d_out, int out_size, void* d_ws, size_t ws_size,
                              hipStream_t stream) {
    const float* x     = (const float*)d_in[0];
    const int* eidx    = (const int*)d_in[1];
    const float* ea    = (const float*)d_in[2];
    const int* batch   = (const int*)d_in[3];
    const float* W0    = (const float*)d_in[4];  const float* b0    = (const float*)d_in[5];
    const float* We1   = (const float*)d_in[6];  const float* be1   = (const float*)d_in[7];
    const float* We2   = (const float*)d_in[8];  const float* be2   = (const float*)d_in[9];
    const float* Wroot = (const float*)d_in[10]; const float* bconv = (const float*)d_in[11];
    const float* Wi    = (const float*)d_in[12]; const float* Wh    = (const float*)d_in[13];
    const float* bi    = (const float*)d_in[14]; const float* bh    = (const float*)d_in[15];
    const float* W11   = (const float*)d_in[16]; const float* b11   = (const float*)d_in[17];
    const float* W12   = (const float*)d_in[18]; const float* b12   = (const float*)d_in[19];
    const float* W13   = (const float*)d_in[20]; const float* b13   = (const float*)d_in[21];
    const float* W21   = (const float*)d_in[22]; const float* b21   = (const float*)d_in[23];
    const float* W22   = (const float*)d_in[24]; const float* b22   = (const float*)d_in[25];
    const float* W23   = (const float*)d_in[26]; const float* b23   = (const float*)d_in[27];
    float* out = (float*)d_out;

    // workspace: total 10,388,480 B
    char* ws = (char*)d_ws;
    float* agg    = (float*)(ws);                       // 6,400,000 B
    u16*   x1b    = (u16*)(ws + 6400000);               // 3,200,000 B
    u16*   Bt     = (u16*)(ws + 9600000);               //   532,480 B
    float* pooled = (float*)(ws + 10132480);            //   256,000 B

    hipLaunchKernelGGL(k_prep, dim3(2048), dim3(256), 0, stream, We2, be2, agg, pooled, Bt);
    hipLaunchKernelGGL(k_lin0, dim3(6250), dim3(256), 0, stream, x, W0, b0, x1b);
    hipLaunchKernelGGL(k_msg, dim3(782), dim3(256), 0, stream, ea, eidx, We1, be1, x1b, Bt, agg);
    hipLaunchKernelGGL(k_gru, dim3(391), dim3(256), 0, stream, x1b, agg, Wroot, bconv,
                       Wi, Wh, bi, bh, batch, pooled);
    hipLaunchKernelGGL(k_heads, dim3(250), dim3(256), 0, stream, pooled,
                       W11, b11, W12, b12, W13, b13, W21, b21, W22, b22, W23, b23, out);
}